// Round 6
// baseline (154.514 us; speedup 1.0000x reference)
//
#include <hip/hip_runtime.h>
#include <hip/hip_bf16.h>

// Problem: B=32, D=2048, NB=16, BS=512 (fp32 I/O)
//   out[b,r] = g[b, r>>7] * dot(W[r,:], x[b,:]) + bias[r]
//   g = sigmoid(x @ gate_w + gate_b); zero the 8 smallest gates per sample.
//
// ONE plain launch, 512 blocks x 256 threads, __launch_bounds__(256,2):
//   2 blocks/CU guaranteed -> all 512 blocks co-resident -> flag spin is safe.
//   All blocks: preload A (4 W rows, full K) into 64 bf16 VGPRs (W HBM stream
//               starts immediately, overlaps gate compute).
//   Blocks 0..31: compute gates[b][16] fp32 + convert X row b to bf16 -> ws,
//               __threadfence, set sentinel flags[b] (agent-scope release).
//   All blocks: poll 32 sentinels (acquire), then B-loads from Xbf + MFMA,
//               LDS reduce, epilogue g*s+bias -> out. No atomics on out.
//   ws poison 0xAAAAAAAA != SENTINEL, so flags need no zero-init.

#define D_DIM 2048
#define B_DIM 32
#define NB_DIM 16
#define SENT 0x5CA1AB1Eu

typedef __attribute__((ext_vector_type(4))) float f32x4;
typedef __attribute__((ext_vector_type(8))) float f32x8;
typedef __attribute__((ext_vector_type(8))) __bf16 bf16x8;

static __device__ __forceinline__ __bf16 f2bf(float f) {
    unsigned u = __builtin_bit_cast(unsigned, f);
    u += 0x7fffu + ((u >> 16) & 1u);           // round-to-nearest-even
    unsigned short h = (unsigned short)(u >> 16);
    return __builtin_bit_cast(__bf16, h);
}

static __device__ __forceinline__ bf16x8 load_cvt8(const float* p) {
    const f32x8 v = *(const f32x8*)p;          // 32B: two dwordx4
    bf16x8 r;
#pragma unroll
    for (int i = 0; i < 8; ++i) r[i] = f2bf(v[i]);
    return r;
}

__global__ __launch_bounds__(256, 2) void fused_kernel(
    const float* __restrict__ X,    // [32][2048]
    const float* __restrict__ GW,   // [2048][16]
    const float* __restrict__ GB,   // [16]
    const float* __restrict__ W,    // [2048][2048]
    const float* __restrict__ bias, // [2048]
    float* __restrict__ gates,      // ws: [32][16]
    __bf16* __restrict__ Xbf,       // ws: [32][2048]
    unsigned* __restrict__ flags,   // ws: [32]
    float* __restrict__ out)        // [32][2048]
{
    __shared__ float smem[NB_DIM * 256 + NB_DIM];   // gates: red[16][256]+sg[16]; gemm: red2[4][4][32]
    const int t    = threadIdx.x;
    const int bi   = blockIdx.x;
    const int wave = t >> 6;
    const int lane = t & 63;
    const int l15  = lane & 15;
    const int q    = lane >> 4;
    const int r0   = bi * 4;
    const int nblk = r0 >> 7;            // 4-row tile never crosses a 128-row gate block
    const int kb   = wave * (D_DIM / 4); // 512 K per wave

    // ---- A-preload: 4 W rows, this wave's K-slice, fp32->bf16, 64 VGPRs live ----
    const float* arow = W + (size_t)(r0 + (l15 & 3)) * D_DIM + kb + q * 8;
    bf16x8 abf[16];
#pragma unroll
    for (int s = 0; s < 16; ++s) abf[s] = load_cvt8(arow + s * 32);

    // ---- Producer blocks: gates (fp32, exact top-8) + X row -> bf16 ----
    if (bi < B_DIM) {
        float* red = smem;                 // [16][256]
        float* sg  = smem + NB_DIM * 256;  // [16]
        const int b = bi;

        {   // convert this sample's X row to bf16
            const int idx = b * D_DIM + t * 8;
            *(bf16x8*)(Xbf + idx) = load_cvt8(X + idx);
        }

        float acc[NB_DIM];
#pragma unroll
        for (int n = 0; n < NB_DIM; ++n) acc[n] = 0.f;
#pragma unroll
        for (int i = 0; i < D_DIM / 256; ++i) {
            const int c = t + i * 256;
            const float xv = X[b * D_DIM + c];
            const float* gw = GW + c * NB_DIM;
#pragma unroll
            for (int n = 0; n < NB_DIM; ++n) acc[n] += xv * gw[n];
        }
#pragma unroll
        for (int n = 0; n < NB_DIM; ++n) red[n * 256 + t] = acc[n];
        __syncthreads();
        for (int s = 128; s > 0; s >>= 1) {
            if (t < s) {
#pragma unroll
                for (int n = 0; n < NB_DIM; ++n) red[n * 256 + t] += red[n * 256 + t + s];
            }
            __syncthreads();
        }
        if (t < NB_DIM) {
            const float v = red[t * 256] + GB[t];
            sg[t] = 1.f / (1.f + __expf(-v));
        }
        __syncthreads();
        if (t < NB_DIM) {
            const float g = sg[t];
            int rank = 0;  // gates smaller (ties: lower index smaller, matches lax.top_k drop)
#pragma unroll
            for (int m = 0; m < NB_DIM; ++m) {
                const float gm = sg[m];
                if (gm < g || (gm == g && m < t)) rank++;
            }
            gates[b * NB_DIM + t] = (rank >= NB_DIM / 2) ? g : 0.f;
        }
        __threadfence();     // drain gates/Xbf stores to device scope
        __syncthreads();     // all stores in this block done before flag
        if (t == 0)
            __hip_atomic_store(&flags[b], SENT, __ATOMIC_RELEASE, __HIP_MEMORY_SCOPE_AGENT);
    }

    // ---- Poll: every wave waits for all 32 producer sentinels ----
    {
        int done = (lane < B_DIM) ? 0 : 1;
        while (!__all(done)) {
            if (lane < B_DIM && !done)
                done = (__hip_atomic_load(&flags[lane], __ATOMIC_ACQUIRE,
                                          __HIP_MEMORY_SCOPE_AGENT) == SENT);
            if (!__all(done)) __builtin_amdgcn_s_sleep(8);
        }
    }

    // ---- MFMA: 4 rows x 32 batches, wave's K-slice of 512 ----
    const __bf16* b0p = Xbf + (size_t)(l15)      * D_DIM + kb + q * 8;
    const __bf16* b1p = Xbf + (size_t)(l15 + 16) * D_DIM + kb + q * 8;

    f32x4 acc0 = {0.f, 0.f, 0.f, 0.f};
    f32x4 acc1 = {0.f, 0.f, 0.f, 0.f};
#pragma unroll
    for (int s = 0; s < 16; ++s) {
        const bf16x8 bv0 = *(const bf16x8*)(b0p + s * 32);
        const bf16x8 bv1 = *(const bf16x8*)(b1p + s * 32);
        acc0 = __builtin_amdgcn_mfma_f32_16x16x32_bf16(abf[s], bv0, acc0, 0, 0, 0);
        acc1 = __builtin_amdgcn_mfma_f32_16x16x32_bf16(abf[s], bv1, acc1, 0, 0, 0);
    }

    // C/D: col = lane&15 (batch), row m = q*4+i; rows duplicated 4x -> q==0 holds all
    __syncthreads();                       // smem handoff (producers reused it for gates)
    float* red2 = smem;                    // [wave][row][batch] = [4][4][32]
    if (q == 0) {
#pragma unroll
        for (int i = 0; i < 4; ++i) {
            red2[wave * 128 + i * 32 + l15]      = acc0[i];
            red2[wave * 128 + i * 32 + 16 + l15] = acc1[i];
        }
    }
    __syncthreads();

    // epilogue: thread b (t<32) writes 4 consecutive rows as f32x4
    if (t < B_DIM) {
        const int b = t;
        f32x4 s;
#pragma unroll
        for (int i = 0; i < 4; ++i) {
            s[i] = red2[0 * 128 + i * 32 + b] + red2[1 * 128 + i * 32 + b] +
                   red2[2 * 128 + i * 32 + b] + red2[3 * 128 + i * 32 + b];
        }
        const float g = gates[b * NB_DIM + nblk];
        const f32x4 bi4 = *(const f32x4*)(bias + r0);
        f32x4 y;
#pragma unroll
        for (int i = 0; i < 4; ++i) y[i] = g * s[i] + bi4[i];
        *(f32x4*)(out + (size_t)b * D_DIM + r0) = y;
    }
}

extern "C" void kernel_launch(void* const* d_in, const int* in_sizes, int n_in,
                              void* d_out, int out_size, void* d_ws, size_t ws_size,
                              hipStream_t stream) {
    const float* x    = (const float*)d_in[0];  // [32][2048]
    const float* gw   = (const float*)d_in[1];  // [2048][16]
    const float* gb   = (const float*)d_in[2];  // [16]
    const float* w    = (const float*)d_in[3];  // [2048][2048]
    const float* bias = (const float*)d_in[4];  // [2048]
    float* out = (float*)d_out;

    __bf16*   Xbf   = (__bf16*)d_ws;                                  // 128 KB
    float*    gates = (float*)((char*)d_ws + 131072);                 // 2 KB
    unsigned* flags = (unsigned*)((char*)d_ws + 131072 + 2048);       // 128 B

    fused_kernel<<<D_DIM / 4, 256, 0, stream>>>(x, gw, gb, w, bias, gates, Xbf, flags, out);
}

// Round 7
// 83.137 us; speedup vs baseline: 1.8585x; 1.8585x over previous
//
#include <hip/hip_runtime.h>
#include <hip/hip_bf16.h>

// Problem: B=32, D=2048, NB=16, BS=512 (fp32 I/O)
//   out[b,r] = g[b, r>>7] * dot(W[r,:], x[b,:]) + bias[r]
//   g = sigmoid(x @ gate_w + gate_b); zero the 8 smallest gates per sample.
//
// Structure = round-2 (best measured: 85 us) with the B-path upgraded:
//   K1 (32 blocks):  gates[32][16] fp32 (exact top-8) + X -> bf16 ws (single RNE cvt)
//   K2 (256 blocks): split-K MFMA partials; A = W fp32->bf16 on the fly,
//                    B = Xbf direct 16B loads (no cvt, half the L2 traffic of r2)
//   K3 (64 blocks):  reduce 8 partials * gate + bias -> out
// No atomics on out, no cooperative launch, no spin (r3/r4/r6 all measured worse).

#define D_DIM 2048
#define B_DIM 32
#define NB_DIM 16
#define KSPLIT 8                   // 32 row-groups x 8 k-slices = 256 blocks
#define KCHUNK (D_DIM / KSPLIT)    // 256

typedef __attribute__((ext_vector_type(4))) float f32x4;
typedef __attribute__((ext_vector_type(8))) float f32x8;
typedef __attribute__((ext_vector_type(8))) __bf16 bf16x8;

static __device__ __forceinline__ __bf16 f2bf(float f) {
    unsigned u = __builtin_bit_cast(unsigned, f);
    u += 0x7fffu + ((u >> 16) & 1u);           // round-to-nearest-even
    unsigned short h = (unsigned short)(u >> 16);
    return __builtin_bit_cast(__bf16, h);
}

static __device__ __forceinline__ bf16x8 load_cvt8(const float* p) {
    const f32x8 v = *(const f32x8*)p;          // 32B: two dwordx4
    bf16x8 r;
#pragma unroll
    for (int i = 0; i < 8; ++i) r[i] = f2bf(v[i]);
    return r;
}

// ---------------- Kernel 1: gates (fp32, exact) + X->bf16 ----------------
__global__ __launch_bounds__(256) void prep_kernel(
    const float* __restrict__ X,    // [32][2048]
    const float* __restrict__ GW,   // [2048][16]
    const float* __restrict__ GB,   // [16]
    float* __restrict__ gates,      // ws: [32][16]
    __bf16* __restrict__ Xbf)       // ws: [32][2048]
{
    __shared__ float red[NB_DIM][256];
    __shared__ float sg[NB_DIM];
    const int b = blockIdx.x;
    const int t = threadIdx.x;

    {   // convert this sample's X row to bf16 (32B loads / 16B stores)
        const int idx = b * D_DIM + t * 8;
        *(bf16x8*)(Xbf + idx) = load_cvt8(X + idx);
    }

    float acc[NB_DIM];
#pragma unroll
    for (int n = 0; n < NB_DIM; ++n) acc[n] = 0.f;

#pragma unroll
    for (int i = 0; i < D_DIM / 256; ++i) {
        const int c = t + i * 256;
        const float xv = X[b * D_DIM + c];
        const float* gw = GW + c * NB_DIM;
#pragma unroll
        for (int n = 0; n < NB_DIM; ++n) acc[n] += xv * gw[n];
    }
#pragma unroll
    for (int n = 0; n < NB_DIM; ++n) red[n][t] = acc[n];
    __syncthreads();
    for (int s = 128; s > 0; s >>= 1) {
        if (t < s) {
#pragma unroll
            for (int n = 0; n < NB_DIM; ++n) red[n][t] += red[n][t + s];
        }
        __syncthreads();
    }
    if (t < NB_DIM) {
        const float v = red[t][0] + GB[t];
        sg[t] = 1.f / (1.f + __expf(-v));
    }
    __syncthreads();
    if (t < NB_DIM) {
        const float g = sg[t];
        int rank = 0;  // gates smaller (ties: lower index smaller, matches lax.top_k drop)
#pragma unroll
        for (int m = 0; m < NB_DIM; ++m) {
            const float gm = sg[m];
            if (gm < g || (gm == g && m < t)) rank++;
        }
        gates[b * NB_DIM + t] = (rank >= NB_DIM / 2) ? g : 0.f;
    }
}

// ---------------- Kernel 2: split-K GEMM partials ----------------
// part[ks][b][r] = sum_{c in slice ks} W[r][c] * x[b][c]
// 256 blocks = 32 row-groups (64 rows) x 8 k-slices; 4 waves/block, wave owns
// 16 rows x all 32 batches. A-frag (16x16x32): lane holds A[m=lane&15][k=(lane>>4)*8+0..7].
__global__ __launch_bounds__(256) void main_gemm(
    const float* __restrict__ W,     // [2048][2048]
    const __bf16* __restrict__ Xbf,  // ws: [32][2048]
    float* __restrict__ part)        // ws: [KSPLIT][32][2048]
{
    const int bid  = blockIdx.x;
    const int ks   = bid & (KSPLIT - 1);
    const int rg   = bid >> 3;
    const int wave = threadIdx.x >> 6;
    const int lane = threadIdx.x & 63;
    const int l15  = lane & 15;
    const int q    = lane >> 4;

    const int r0 = rg * 64 + wave * 16;
    const int k0 = ks * KCHUNK;

    const float*  arow = W   + (size_t)(r0 + l15) * D_DIM + k0 + q * 8;
    const __bf16* b0p  = Xbf + (size_t)(l15)      * D_DIM + k0 + q * 8;
    const __bf16* b1p  = Xbf + (size_t)(l15 + 16) * D_DIM + k0 + q * 8;

    f32x4 acc0 = {0.f, 0.f, 0.f, 0.f};
    f32x4 acc1 = {0.f, 0.f, 0.f, 0.f};

#pragma unroll
    for (int kk = 0; kk < KCHUNK / 32; ++kk) {   // 8 MFMA k-steps
        const bf16x8 av  = load_cvt8(arow + kk * 32);
        const bf16x8 bv0 = *(const bf16x8*)(b0p + kk * 32);
        const bf16x8 bv1 = *(const bf16x8*)(b1p + kk * 32);
        acc0 = __builtin_amdgcn_mfma_f32_16x16x32_bf16(av, bv0, acc0, 0, 0, 0);
        acc1 = __builtin_amdgcn_mfma_f32_16x16x32_bf16(av, bv1, acc1, 0, 0, 0);
    }

    // C/D: col(batch) = lane&15, row(W-row) = (lane>>4)*4 + reg
    float* p0 = part + (size_t)ks * (B_DIM * D_DIM) + (size_t)l15 * D_DIM        + r0 + q * 4;
    float* p1 = part + (size_t)ks * (B_DIM * D_DIM) + (size_t)(l15 + 16) * D_DIM + r0 + q * 4;
    *(f32x4*)p0 = acc0;
    *(f32x4*)p1 = acc1;
}

// ---------------- Kernel 3: reduce + gate + bias -> out ----------------
__global__ __launch_bounds__(256) void reduce_kernel(
    const float* __restrict__ part,   // ws: [KSPLIT][32][2048]
    const float* __restrict__ gates,  // ws: [32][16]
    const float* __restrict__ bias,   // [2048]
    float* __restrict__ out)          // [32][2048]
{
    const int t   = blockIdx.x * 256 + threadIdx.x;   // 16384 threads
    const int idx = t * 4;
    const int b   = idx >> 11;
    const int r   = idx & (D_DIM - 1);

    f32x4 s = {0.f, 0.f, 0.f, 0.f};
#pragma unroll
    for (int ks = 0; ks < KSPLIT; ++ks) {
        s += *(const f32x4*)(part + (size_t)ks * (B_DIM * D_DIM) + idx);
    }
    const float g = gates[b * NB_DIM + (r >> 7)];
    const f32x4 bi = *(const f32x4*)(bias + r);

    f32x4 y;
#pragma unroll
    for (int i = 0; i < 4; ++i) y[i] = g * s[i] + bi[i];
    *(f32x4*)(out + idx) = y;
}

extern "C" void kernel_launch(void* const* d_in, const int* in_sizes, int n_in,
                              void* d_out, int out_size, void* d_ws, size_t ws_size,
                              hipStream_t stream) {
    const float* x    = (const float*)d_in[0];  // [32][2048]
    const float* gw   = (const float*)d_in[1];  // [2048][16]
    const float* gb   = (const float*)d_in[2];  // [16]
    const float* w    = (const float*)d_in[3];  // [2048][2048]
    const float* bias = (const float*)d_in[4];  // [2048]
    float* out = (float*)d_out;

    float*  part  = (float*)d_ws;                              // 8*32*2048 fp32 = 2 MB
    float*  gates = (float*)((char*)d_ws + 2097152);           // 2 KB
    __bf16* Xbf   = (__bf16*)((char*)d_ws + 2097152 + 4096);   // 128 KB

    prep_kernel<<<B_DIM, 256, 0, stream>>>(x, gw, gb, gates, Xbf);
    main_gemm<<<32 * KSPLIT, 256, 0, stream>>>(w, Xbf, part);
    reduce_kernel<<<(B_DIM * D_DIM) / (256 * 4), 256, 0, stream>>>(part, gates, bias, out);
}